// Round 1
// 502.309 us; speedup vs baseline: 1.0301x; 1.0301x over previous
//
#include <hip/hip_runtime.h>
#include <hip/hip_bf16.h>

// ---------------------------------------------------------------------------
// PUSCH neural detector: 4 stacked ConvLSTM layers on [B=2,T=14,H=1536,W=1].
// 3x3 conv degenerates to width-3 conv along H (kw=1 slice).
// R11: trapezoidal scan (zero inter-block sync). R12: xz_gemm rewrite —
// counters showed it LDS-BW-bound (152KB LDS traffic / 144 MFMAs per chunk,
// MfmaUtil 21%, bank-conflict cycles = 26% of CU-cycles). Now: 64x128 block
// tile (4mt x 2nt per wave, z-grid halved) for 1.67x less LDS-read/FLOP,
// conflict-free staging-row permutation (phase rows {r,r+2,r+4,r+6} ->
// 2 lanes/bank uniform), and register double-buffer prefetch (T14) so global
// loads overlap the MFMA phase.
// ---------------------------------------------------------------------------

#define BB   2
#define TT   14
#define LL   1536
#define CINR 297
#define CP_IN 320                 // padded input channels (10 chunks of 32)
#define NSTRIP 96                 // LL / 16
#define NBLK  (BB * NSTRIP)       // 192 scan blocks
#define WIN  48                   // scan window rows (own 16 + 16 halo each side)

typedef __attribute__((ext_vector_type(8))) short short8;   // 8 bf16 = 4 VGPRs
typedef __attribute__((ext_vector_type(4))) float floatx4;  // MFMA C/D

// ---- workspace layout -----------------------------------------------------
static constexpr size_t U_WBIN_HI  = 0;         // [256][960]
static constexpr size_t U_WBIN_LO  = 245760;
static constexpr size_t U_WBR0_HI  = 491520;    // [256][192]
static constexpr size_t U_WBR0_LO  = 540672;
static constexpr size_t U_WBR1_HI  = 589824;
static constexpr size_t U_WBR1_LO  = 638976;
static constexpr size_t U_WBOUT_HI = 688128;    // [128][192]
static constexpr size_t U_WBOUT_LO = 712704;
static constexpr size_t U_WHTIN    = 737280;    // [256][192] scan WhT bf16
static constexpr size_t U_WHTR0    = 786432;
static constexpr size_t U_WHTR1    = 835584;
static constexpr size_t U_WHTOUT   = 884736;    // [128][96]
static constexpr size_t OFF_BIN   = 448512;     // f32 gate-interleaved biases
static constexpr size_t OFF_BR0   = 448768;
static constexpr size_t OFF_BR1   = 449024;
static constexpr size_t OFF_BOUT  = 449280;
static constexpr size_t OFF_Z0HI  = 458752;     // u16 plane [28][1536][320]
static constexpr size_t SZ_Z0PL   = 6881280;
static constexpr size_t OFF_Z0LO  = OFF_Z0HI + SZ_Z0PL;
static constexpr size_t OFF_XZ    = OFF_Z0LO + SZ_Z0PL;
static constexpr size_t SZ_XZ     = (size_t)BB*TT*LL*256;
// seq aliases the dead z0 region after the layer-in GEMM:
static constexpr size_t OFF_SEQ   = OFF_Z0HI;               // f32 [28][1536][64]
static constexpr size_t OFF_SEQHI = OFF_SEQ + (size_t)BB*TT*LL*64;
static constexpr size_t OFF_SEQLO = OFF_SEQHI + (size_t)BB*TT*LL*32;
// total ~101 MB

__device__ __forceinline__ float hsig(float x) {
    return fminf(fmaxf(0.2f * x + 0.5f, 0.0f), 1.0f);
}
__device__ __forceinline__ float ftanh(float x) {
    // tanh(x) = 1 - 2/(e^{2x}+1); bounded, finite-in -> finite-out.
    float e = __expf(2.0f * x);
    return 1.0f - 2.0f / (e + 1.0f);
}
__device__ __forceinline__ unsigned short f2bf(float x) {
    unsigned int u = __builtin_bit_cast(unsigned int, x);
    u += 0x7fffu + ((u >> 16) & 1u);          // RNE
    return (unsigned short)(u >> 16);
}
__device__ __forceinline__ float bf2f(unsigned short h) {
    unsigned int u = ((unsigned int)h) << 16;
    return __builtin_bit_cast(float, u);
}

// ---------------------------------------------------------------------------
// prep_weights (unchanged from R10).
// ---------------------------------------------------------------------------
__global__ __launch_bounds__(256)
void prep_weights_kernel(const float* wx_in, const float* wh_in, const float* b_in,
                         const float* wx_r0, const float* wh_r0, const float* b_r0,
                         const float* wx_r1, const float* wh_r1, const float* b_r1,
                         const float* wx_out, const float* wh_out, const float* b_out,
                         float* __restrict__ ws)
{
    int idx = blockIdx.x * 256 + threadIdx.x;
    unsigned short* u = (unsigned short*)ws;
    if (idx < 245760) {                         // WBIN [256][960]
        int n = idx / 960, k = idx % 960;
        int kh = k / CP_IN, ci = k % CP_IN;
        float v = 0.0f;
        if (ci < CINR) {
            int f = n >> 2, g = n & 3;
            v = wx_in[((size_t)(kh * 3 + 1) * CINR + ci) * 256 + g * 64 + f];
        }
        unsigned short hi = f2bf(v);
        u[U_WBIN_HI + idx] = hi;
        u[U_WBIN_LO + idx] = f2bf(v - bf2f(hi));
        return;
    }
    idx -= 245760;
    if (idx < 49152) {                          // WBR0 [256][192]
        int n = idx / 192, k = idx % 192;
        int kh = k >> 6, ci = k & 63;
        int f = n >> 2, g = n & 3;
        float v = wx_r0[((size_t)(kh * 3 + 1) * 64 + ci) * 256 + g * 64 + f];
        unsigned short hi = f2bf(v);
        u[U_WBR0_HI + idx] = hi;
        u[U_WBR0_LO + idx] = f2bf(v - bf2f(hi));
        return;
    }
    idx -= 49152;
    if (idx < 49152) {                          // WBR1
        int n = idx / 192, k = idx % 192;
        int kh = k >> 6, ci = k & 63;
        int f = n >> 2, g = n & 3;
        float v = wx_r1[((size_t)(kh * 3 + 1) * 64 + ci) * 256 + g * 64 + f];
        unsigned short hi = f2bf(v);
        u[U_WBR1_HI + idx] = hi;
        u[U_WBR1_LO + idx] = f2bf(v - bf2f(hi));
        return;
    }
    idx -= 49152;
    if (idx < 24576) {                          // WBOUT [128][192]
        int n = idx / 192, k = idx % 192;
        int kh = k >> 6, ci = k & 63;
        int f = n >> 2, g = n & 3;
        float v = wx_out[((size_t)(kh * 3 + 1) * 64 + ci) * 128 + g * 32 + f];
        unsigned short hi = f2bf(v);
        u[U_WBOUT_HI + idx] = hi;
        u[U_WBOUT_LO + idx] = f2bf(v - bf2f(hi));
        return;
    }
    idx -= 24576;
    if (idx < 49152) {                          // WHTIN [256][192]
        int n = idx / 192, k = idx % 192, kh = k >> 6, ci = k & 63;
        u[U_WHTIN + idx] = f2bf(wh_in[((size_t)(kh * 3 + 1) * 64 + ci) * 256 + n]);
        return;
    }
    idx -= 49152;
    if (idx < 49152) {
        int n = idx / 192, k = idx % 192, kh = k >> 6, ci = k & 63;
        u[U_WHTR0 + idx] = f2bf(wh_r0[((size_t)(kh * 3 + 1) * 64 + ci) * 256 + n]);
        return;
    }
    idx -= 49152;
    if (idx < 49152) {
        int n = idx / 192, k = idx % 192, kh = k >> 6, ci = k & 63;
        u[U_WHTR1 + idx] = f2bf(wh_r1[((size_t)(kh * 3 + 1) * 64 + ci) * 256 + n]);
        return;
    }
    idx -= 49152;
    if (idx < 12288) {                          // WHTOUT [128][96]
        int n = idx / 96, k = idx % 96, kh = k / 32, ci = k % 32;
        u[U_WHTOUT + idx] = f2bf(wh_out[((size_t)(kh * 3 + 1) * 32 + ci) * 128 + n]);
        return;
    }
    idx -= 12288;
    if (idx < 256) { int f = idx >> 2, g = idx & 3; ws[OFF_BIN + idx] = b_in[g * 64 + f]; return; }
    idx -= 256;
    if (idx < 256) { int f = idx >> 2, g = idx & 3; ws[OFF_BR0 + idx] = b_r0[g * 64 + f]; return; }
    idx -= 256;
    if (idx < 256) { int f = idx >> 2, g = idx & 3; ws[OFF_BR1 + idx] = b_r1[g * 64 + f]; return; }
    idx -= 256;
    if (idx < 128) { int f = idx >> 2, g = idx & 3; ws[OFF_BOUT + idx] = b_out[g * 32 + f]; return; }
}

// ---------------------------------------------------------------------------
// build_features (unchanged from R10): gather -> z0 bf16 hi/lo [28][1536][320]
// ---------------------------------------------------------------------------
__global__ __launch_bounds__(256)
void build_features_kernel(const float* __restrict__ y,
                           const float* __restrict__ h,
                           const float* __restrict__ ev,
                           const float* __restrict__ no,
                           unsigned short* __restrict__ z0hi,
                           unsigned short* __restrict__ z0lo)
{
    long long idx = (long long)blockIdx.x * 256 + threadIdx.x;
    const long long total = (long long)BB * TT * LL * CP_IN;
    if (idx >= total) return;
    int c = (int)(idx % CP_IN);
    long long rest = idx / CP_IN;
    int l = (int)(rest % LL); rest /= LL;
    int t = (int)(rest % TT);
    int b = (int)(rest / TT);
    float v = 0.0f;
    if (c < 32) {
        int na = c >> 1, ri = c & 1;
        v = y[((((long long)b * 16 + na) * TT + t) * LL + l) * 2 + ri];
    } else if (c < 288) {
        int q = c - 32;
        int ri = q & 1, nspu = (q >> 1) & 1, nue = (q >> 2) & 3, na = q >> 4;
        v = h[((((((long long)b * 16 + na) * 4 + nue) * 2 + nspu) * TT + t) * LL + l) * 2 + ri];
    } else if (c < 296) {
        int q = c - 288; int nspu = q & 1, nue = q >> 1;
        v = ev[(((long long)(nue * 2 + nspu) * TT + t) * LL) + l];
    } else if (c == 296) {
        v = no[0];
    }
    unsigned short hi = f2bf(v);
    z0hi[idx] = hi;
    z0lo[idx] = f2bf(v - bf2f(hi));
}

// ---------------------------------------------------------------------------
// xz_gemm_mfma R12: split-bf16 MFMA conv-GEMM, 64x128 block tile.
// 4 waves, each 4mt x 2nt (64 rows x 32 cols) -> 36 frag reads / 72 MFMAs
// per chunk per wave (was 30/36). Staging rows permuted so each 16-lane
// write phase hits {0,32,64,96} mod 128B (2 lanes/bank, free). Next chunk
// prefetched into registers during the MFMA phase (T14 async split).
// Accumulation order per output element identical to R10 (bit-exact).
// ---------------------------------------------------------------------------
__global__ __launch_bounds__(256)
void xz_gemm_mfma_kernel(const unsigned short* __restrict__ Ahi,
                         const unsigned short* __restrict__ Alo,
                         int Cpitch,
                         const unsigned short* __restrict__ Bhi,
                         const unsigned short* __restrict__ Blo,
                         const float* __restrict__ bias,
                         float* __restrict__ out, int Ncol)
{
    __shared__ unsigned short AsHi[66 * 40], AsLo[66 * 40];
    __shared__ unsigned short WsHi[3 * 128 * 40], WsLo[3 * 128 * 40];
    const int tid  = threadIdx.x;
    const int lane = tid & 63;
    const int wv   = tid >> 6;
    const int m    = lane & 15;
    const int quad = lane >> 4;
    const int bt   = blockIdx.y;
    const int l0   = blockIdx.x * 64;
    const int n0   = blockIdx.z * 128;
    const int K    = 3 * Cpitch;
    const int NC   = Cpitch >> 5;

    // --- staging slot geometry (conflict-free row permutation) -------------
    // A: 66 rows x 4 16B-cols = 264 slots (tid + tail tid<8).
    // W: 384 rows x 4        = 1536 slots (tid + k*256, k=0..5).
    // perm: 16 consecutive threads -> rows {r, r+2, r+4, r+6}; with the 80B
    // row stride their 64B segments start at {0,32,64,96} mod 128.
    const int aC8   = (tid & 3) * 8;
    const int aRow  = (tid >> 5) * 8 + ((tid >> 2) & 3) * 2 + ((tid >> 4) & 1);
    const int aRowT = 64 + ((tid >> 2) & 1);          // tail rows 64/65 (tid<8)

    int wRow[6], wKh[6], wNn[6];
#pragma unroll
    for (int k = 0; k < 6; ++k) {
        const int s = tid + k * 256;
        const int r = (s >> 5) * 8 + ((s >> 2) & 3) * 2 + ((s >> 4) & 1);
        wRow[k] = r; wKh[k] = r >> 7; wNn[k] = r & 127;
    }

    short8 aH0 = (short8)0, aL0 = (short8)0, aH1 = (short8)0, aL1 = (short8)0;
    short8 wH[6], wL[6];

    // ---- prefetch chunk 0 into registers ----------------------------------
    {
        const int row = l0 + aRow - 1;
        if (row >= 0 && row < LL) {
            size_t off = ((size_t)bt * LL + row) * Cpitch + aC8;
            aH0 = *reinterpret_cast<const short8*>(&Ahi[off]);
            aL0 = *reinterpret_cast<const short8*>(&Alo[off]);
        }
        if (tid < 8) {
            const int rowt = l0 + aRowT - 1;
            if (rowt >= 0 && rowt < LL) {
                size_t off = ((size_t)bt * LL + rowt) * Cpitch + aC8;
                aH1 = *reinterpret_cast<const short8*>(&Ahi[off]);
                aL1 = *reinterpret_cast<const short8*>(&Alo[off]);
            }
        }
#pragma unroll
        for (int k = 0; k < 6; ++k) {
            size_t off = (size_t)(n0 + wNn[k]) * K + (size_t)wKh[k] * Cpitch + aC8;
            wH[k] = *reinterpret_cast<const short8*>(&Bhi[off]);
            wL[k] = *reinterpret_cast<const short8*>(&Blo[off]);
        }
    }

    floatx4 acc[4][2];
#pragma unroll
    for (int i = 0; i < 4; i++)
#pragma unroll
        for (int j = 0; j < 2; j++) acc[i][j] = (floatx4){0.f, 0.f, 0.f, 0.f};

    for (int cc = 0; cc < NC; ++cc) {
        __syncthreads();                 // previous chunk's LDS reads done
        // ---- registers -> LDS (conflict-free rows) ----
        *reinterpret_cast<short8*>(&AsHi[aRow * 40 + aC8]) = aH0;
        *reinterpret_cast<short8*>(&AsLo[aRow * 40 + aC8]) = aL0;
        if (tid < 8) {
            *reinterpret_cast<short8*>(&AsHi[aRowT * 40 + aC8]) = aH1;
            *reinterpret_cast<short8*>(&AsLo[aRowT * 40 + aC8]) = aL1;
        }
#pragma unroll
        for (int k = 0; k < 6; ++k) {
            *reinterpret_cast<short8*>(&WsHi[wRow[k] * 40 + aC8]) = wH[k];
            *reinterpret_cast<short8*>(&WsLo[wRow[k] * 40 + aC8]) = wL[k];
        }
        // ---- issue next chunk's global loads (hide under MFMA phase) ----
        if (cc + 1 < NC) {
            const int c32 = (cc + 1) * 32;
            const int row = l0 + aRow - 1;
            aH0 = (short8)0; aL0 = (short8)0;
            if (row >= 0 && row < LL) {
                size_t off = ((size_t)bt * LL + row) * Cpitch + c32 + aC8;
                aH0 = *reinterpret_cast<const short8*>(&Ahi[off]);
                aL0 = *reinterpret_cast<const short8*>(&Alo[off]);
            }
            if (tid < 8) {
                aH1 = (short8)0; aL1 = (short8)0;
                const int rowt = l0 + aRowT - 1;
                if (rowt >= 0 && rowt < LL) {
                    size_t off = ((size_t)bt * LL + rowt) * Cpitch + c32 + aC8;
                    aH1 = *reinterpret_cast<const short8*>(&Ahi[off]);
                    aL1 = *reinterpret_cast<const short8*>(&Alo[off]);
                }
            }
#pragma unroll
            for (int k = 0; k < 6; ++k) {
                size_t off = (size_t)(n0 + wNn[k]) * K + (size_t)wKh[k] * Cpitch + c32 + aC8;
                wH[k] = *reinterpret_cast<const short8*>(&Bhi[off]);
                wL[k] = *reinterpret_cast<const short8*>(&Blo[off]);
            }
        }
        __syncthreads();                 // LDS tile ready
        // ---- MFMA phase: 3 kh x 4 mt x 2 nt x 3 (split-bf16 triple) ----
#pragma unroll
        for (int kh = 0; kh < 3; ++kh) {
            const int b0 = (kh * 128 + wv * 16 + m) * 40 + quad * 8;
            const int b1 = (kh * 128 + 64 + wv * 16 + m) * 40 + quad * 8;
            const short8 bh0 = *reinterpret_cast<const short8*>(&WsHi[b0]);
            const short8 bl0 = *reinterpret_cast<const short8*>(&WsLo[b0]);
            const short8 bh1 = *reinterpret_cast<const short8*>(&WsHi[b1]);
            const short8 bl1 = *reinterpret_cast<const short8*>(&WsLo[b1]);
#pragma unroll
            for (int mt = 0; mt < 4; ++mt) {
                const int aofs = (mt * 16 + m + kh) * 40 + quad * 8;
                const short8 ah = *reinterpret_cast<const short8*>(&AsHi[aofs]);
                const short8 al = *reinterpret_cast<const short8*>(&AsLo[aofs]);
                acc[mt][0] = __builtin_amdgcn_mfma_f32_16x16x32_bf16(al, bh0, acc[mt][0], 0, 0, 0);
                acc[mt][0] = __builtin_amdgcn_mfma_f32_16x16x32_bf16(ah, bl0, acc[mt][0], 0, 0, 0);
                acc[mt][0] = __builtin_amdgcn_mfma_f32_16x16x32_bf16(ah, bh0, acc[mt][0], 0, 0, 0);
                acc[mt][1] = __builtin_amdgcn_mfma_f32_16x16x32_bf16(al, bh1, acc[mt][1], 0, 0, 0);
                acc[mt][1] = __builtin_amdgcn_mfma_f32_16x16x32_bf16(ah, bl1, acc[mt][1], 0, 0, 0);
                acc[mt][1] = __builtin_amdgcn_mfma_f32_16x16x32_bf16(ah, bh1, acc[mt][1], 0, 0, 0);
            }
        }
    }
    // ---- epilogue ----
#pragma unroll
    for (int nt = 0; nt < 2; ++nt) {
        const int col = n0 + nt * 64 + wv * 16 + m;
        const float bv = bias[col];
#pragma unroll
        for (int mt = 0; mt < 4; ++mt) {
#pragma unroll
            for (int reg = 0; reg < 4; ++reg) {
                int l = l0 + mt * 16 + quad * 4 + reg;
                out[((size_t)bt * LL + l) * Ncol + col] = acc[mt][nt][reg] + bv;
            }
        }
    }
}

// ---------------------------------------------------------------------------
// lstm_scan v3 (trapezoid): 14 steps, ZERO inter-block sync. (unchanged R11)
// ---------------------------------------------------------------------------
template <int F_, bool RESID, bool OUTW>
__global__ __launch_bounds__(64 * (F_ / 16))
void lstm_scan_kernel(const float* __restrict__ xz,           // [28][1536][4F] co'=f*4+g
                      const unsigned short* __restrict__ WhT, // [4F][3F] bf16
                      float* seq,                             // f32 layer in/out (or null)
                      unsigned short* __restrict__ seqhb,     // bf16 hi out (or null)
                      unsigned short* __restrict__ seqlb,     // bf16 lo out (or null)
                      float* __restrict__ dout)               // final out (or null)
{
    constexpr int NW = F_ / 16;
    constexpr int NT = 64 * NW;
    constexpr int K  = 3 * F_;
    constexpr int KS = K / 32;          // 6 (F=64) / 3 (F=32)
    constexpr int KH = KS / 3;          // 2 / 1
    constexpr int HP = F_ + 8;
    __shared__ unsigned short Hs[2][(WIN + 2) * HP];

    const int tid  = threadIdx.x;
    const int lane = tid & 63;
    const int wv   = tid >> 6;
    const int m    = lane & 15;
    const int quad = lane >> 4;
    const int blk  = blockIdx.x;
    const int b    = blk / NSTRIP;
    const int o0   = (blk % NSTRIP) * 16;   // own rows [o0, o0+16)
    const int f    = wv * 16 + m;

    // B-fragments resident for the whole scan
    short8 bfr[4][KS];
#pragma unroll
    for (int g = 0; g < 4; g++)
#pragma unroll
        for (int ks = 0; ks < KS; ks++) {
            const int n  = g * F_ + f;
            const int k0 = ks * 32 + quad * 8;
            bfr[g][ks] = *reinterpret_cast<const short8*>(&WhT[(size_t)n * K + k0]);
        }

    for (int idx = tid; idx < (WIN + 2) * HP; idx += NT) {
        Hs[0][idx] = 0; Hs[1][idx] = 0;     // halo slots stay 0 forever
    }
    __syncthreads();

    float c[3][4];
#pragma unroll
    for (int i = 0; i < 3; i++)
#pragma unroll
        for (int j = 0; j < 4; j++) c[i][j] = 0.0f;

    int cur = 0;
    for (int t = 0; t < TT; ++t) {
        const size_t btL = ((size_t)b * TT + t) * LL;

        // prefetch xz for the whole step (predicated: image bounds + frontier)
        float4 xzv[3][4];
        float  rsv[4];
#pragma unroll
        for (int mt = 0; mt < 3; ++mt)
#pragma unroll
            for (int reg = 0; reg < 4; ++reg) {
                const int w = mt * 16 + quad * 4 + reg;
                const int l = o0 - 16 + w;
                float4 v = make_float4(0.f, 0.f, 0.f, 0.f);
                if (l >= 0 && l < LL && w >= t && w < WIN - t)
                    v = *reinterpret_cast<const float4*>(
                        &xz[(btL + l) * (size_t)(4 * F_) + f * 4]);
                xzv[mt][reg] = v;
            }
        if (RESID) {
#pragma unroll
            for (int reg = 0; reg < 4; ++reg) {
                const int l = o0 + quad * 4 + reg;          // own rows (mt=1)
                rsv[reg] = seq[(btL + l) * F_ + f];
            }
        }

        const int nxt = cur ^ 1;
#pragma unroll
        for (int mt = 0; mt < 3; ++mt) {
            floatx4 zi = {0.f, 0.f, 0.f, 0.f};
            floatx4 zf = {0.f, 0.f, 0.f, 0.f};
            floatx4 zg = {0.f, 0.f, 0.f, 0.f};
            floatx4 zo = {0.f, 0.f, 0.f, 0.f};
            if (t > 0) {
#pragma unroll
                for (int kh = 0; kh < 3; kh++) {
#pragma unroll
                    for (int hf = 0; hf < KH; hf++) {
                        const short8 af = *reinterpret_cast<const short8*>(
                            &Hs[cur][(mt * 16 + m + kh) * HP + hf * 32 + quad * 8]);
                        const int ks = kh * KH + hf;
                        zi = __builtin_amdgcn_mfma_f32_16x16x32_bf16(af, bfr[0][ks], zi, 0, 0, 0);
                        zf = __builtin_amdgcn_mfma_f32_16x16x32_bf16(af, bfr[1][ks], zf, 0, 0, 0);
                        zg = __builtin_amdgcn_mfma_f32_16x16x32_bf16(af, bfr[2][ks], zg, 0, 0, 0);
                        zo = __builtin_amdgcn_mfma_f32_16x16x32_bf16(af, bfr[3][ks], zo, 0, 0, 0);
                    }
                }
            }
#pragma unroll
            for (int reg = 0; reg < 4; ++reg) {
                const int w = mt * 16 + quad * 4 + reg;
                const int l = o0 - 16 + w;
                const bool valid = (l >= 0 && l < LL);
                const float4 z4 = xzv[mt][reg];
                const float ig = hsig(z4.x + zi[reg]);
                const float fg = hsig(z4.y + zf[reg]);
                const float gg = ftanh(z4.z + zg[reg]);
                const float og = hsig(z4.w + zo[reg]);
                float cn = fg * c[mt][reg] + ig * gg;
                float hn = og * ftanh(cn);
                if (!valid) { cn = 0.0f; hn = 0.0f; }   // exact conv pad
                c[mt][reg] = cn;
                Hs[nxt][(1 + w) * HP + f] = f2bf(hn);
                if (w >= 16 && w < 32) {                // own rows -> outputs
                    if (OUTW) {
                        const int ue = f >> 3, spu = (f >> 2) & 1, bit = f & 3;
                        const size_t n = (size_t)t * LL + l;
                        dout[(((size_t)b * 4 + ue) * 2 + spu) * ((size_t)TT * LL * 4)
                             + n * 4 + bit] = hn;
                    } else {
                        float v = hn;
                        if (RESID) v += rsv[reg];
                        seq[(btL + l) * F_ + f] = v;
                        const unsigned short hi = f2bf(v);
                        seqhb[(btL + l) * F_ + f] = hi;
                        seqlb[(btL + l) * F_ + f] = f2bf(v - bf2f(hi));
                    }
                }
            }
        }
        __syncthreads();        // Hs[nxt] complete before next step reads it
        cur = nxt;
    }
}

// ---------------------------------------------------------------------------
extern "C" void kernel_launch(void* const* d_in, const int* in_sizes, int n_in,
                              void* d_out, int out_size, void* d_ws, size_t ws_size,
                              hipStream_t stream)
{
    (void)in_sizes; (void)n_in; (void)out_size; (void)ws_size;
    const float* y_ri   = (const float*)d_in[0];
    const float* h_ri   = (const float*)d_in[1];
    const float* evar   = (const float*)d_in[2];
    const float* no     = (const float*)d_in[3];
    const float* wx_in  = (const float*)d_in[4];
    const float* wh_in  = (const float*)d_in[5];
    const float* b_in   = (const float*)d_in[6];
    const float* wx_r0  = (const float*)d_in[7];
    const float* wh_r0  = (const float*)d_in[8];
    const float* b_r0   = (const float*)d_in[9];
    const float* wx_r1  = (const float*)d_in[10];
    const float* wh_r1  = (const float*)d_in[11];
    const float* b_r1   = (const float*)d_in[12];
    const float* wx_out = (const float*)d_in[13];
    const float* wh_out = (const float*)d_in[14];
    const float* b_out  = (const float*)d_in[15];

    float* ws = (float*)d_ws;
    unsigned short* wu = (unsigned short*)d_ws;
    float* dout = (float*)d_out;

    prep_weights_kernel<<<2068, 256, 0, stream>>>(
        wx_in, wh_in, b_in, wx_r0, wh_r0, b_r0,
        wx_r1, wh_r1, b_r1, wx_out, wh_out, b_out, ws);
    {
        long long total = (long long)BB * TT * LL * CP_IN;
        int blocks = (int)((total + 255) / 256);
        build_features_kernel<<<blocks, 256, 0, stream>>>(
            y_ri, h_ri, evar, no,
            (unsigned short*)(ws + OFF_Z0HI), (unsigned short*)(ws + OFF_Z0LO));
    }

    float* xz    = ws + OFF_XZ;
    float* seq   = ws + OFF_SEQ;
    unsigned short* seqhb = (unsigned short*)(ws + OFF_SEQHI);
    unsigned short* seqlb = (unsigned short*)(ws + OFF_SEQLO);

    const dim3 gIn(LL / 64, BB * TT, 2);    // N=256, 128 cols/block
    const dim3 gO (LL / 64, BB * TT, 1);    // N=128, 128 cols/block

    // ---- layer in: Cin=297(p320) -> F=64
    xz_gemm_mfma_kernel<<<gIn, 256, 0, stream>>>(
        (unsigned short*)(ws + OFF_Z0HI), (unsigned short*)(ws + OFF_Z0LO), CP_IN,
        wu + U_WBIN_HI, wu + U_WBIN_LO, ws + OFF_BIN, xz, 256);
    lstm_scan_kernel<64, false, false><<<NBLK, 256, 0, stream>>>(
        xz, wu + U_WHTIN, seq, seqhb, seqlb, nullptr);

    // ---- layer r0 (+residual, in-place on seq)
    xz_gemm_mfma_kernel<<<gIn, 256, 0, stream>>>(
        seqhb, seqlb, 64, wu + U_WBR0_HI, wu + U_WBR0_LO, ws + OFF_BR0, xz, 256);
    lstm_scan_kernel<64, true, false><<<NBLK, 256, 0, stream>>>(
        xz, wu + U_WHTR0, seq, seqhb, seqlb, nullptr);

    // ---- layer r1 (+residual, in-place on seq)
    xz_gemm_mfma_kernel<<<gIn, 256, 0, stream>>>(
        seqhb, seqlb, 64, wu + U_WBR1_HI, wu + U_WBR1_LO, ws + OFF_BR1, xz, 256);
    lstm_scan_kernel<64, true, false><<<NBLK, 256, 0, stream>>>(
        xz, wu + U_WHTR1, seq, seqhb, seqlb, nullptr);

    // ---- layer out: F=32, writes d_out (f32, transposed layout)
    xz_gemm_mfma_kernel<<<gO, 256, 0, stream>>>(
        seqhb, seqlb, 64, wu + U_WBOUT_HI, wu + U_WBOUT_LO, ws + OFF_BOUT, xz, 128);
    lstm_scan_kernel<32, false, true><<<NBLK, 128, 0, stream>>>(
        xz, wu + U_WHTOUT, nullptr, nullptr, nullptr, dout);
}